// Round 4
// baseline (227.483 us; speedup 1.0000x reference)
//
#include <hip/hip_runtime.h>
#include <hip/hip_bf16.h>
#include <stdint.h>
#include <math.h>

typedef __bf16 bf16;
typedef __bf16 bf16x8 __attribute__((ext_vector_type(8)));
typedef float f32x4 __attribute__((ext_vector_type(4)));

#define QSCALE 0.1803368801111f  /* 0.125 * log2(e) */

// B=8, N=1025 (32*32+1), DIM=512, HEADS=12, DH=64, INNER=768
// M = 8*1025 = 8200, padded to 8320 (65*128). N per (b,h) padded to 1088 (17*64).

__device__ __forceinline__ void gload_lds16(const void* g, void* l) {
  typedef const __attribute__((address_space(1))) char g_char;
  typedef __attribute__((address_space(3))) char l_char;
  g_char* gp = (g_char*)(uintptr_t)g;
  l_char* lp = (l_char*)(uint32_t)(uintptr_t)l;
  __builtin_amdgcn_global_load_lds(gp, lp, 16, 0, 0);
}

__device__ __forceinline__ float fexp2(float x) {
#if __has_builtin(__builtin_amdgcn_exp2f)
  return __builtin_amdgcn_exp2f(x);
#else
  return exp2f(x);
#endif
}

__device__ __forceinline__ float frcp(float x) {
#if __has_builtin(__builtin_amdgcn_rcpf)
  return __builtin_amdgcn_rcpf(x);
#else
  return 1.f / x;
#endif
}

__device__ __forceinline__ uint32_t pk2(float a, float b) {
  union { bf16 h; unsigned short u; } ua, ub;
  ua.h = (bf16)a; ub.h = (bf16)b;
  return (uint32_t)ua.u | ((uint32_t)ub.u << 16);
}

// Fused prep: x->xb (pad to 8320 rows), w_qkv->bf16, w_out->bf16, zero vT tail cols [1024,1088).
__global__ __launch_bounds__(256) void k_prep(const float* __restrict__ x,
                                              const float* __restrict__ wqkv,
                                              const float* __restrict__ wout,
                                              bf16* __restrict__ xb, bf16* __restrict__ wqkvb,
                                              bf16* __restrict__ woutb, bf16* __restrict__ vT) {
  int i = blockIdx.x * 256 + threadIdx.x;
  const float* src = nullptr;
  bf16* dst = nullptr;
  int q = i;
  bool zero = false;
  if (i < 1064960) {
    if (i < 1049600) src = x; else zero = true;
    dst = xb;
  } else if (i < 1064960 + 294912) {
    q = i - 1064960; src = wqkv; dst = wqkvb;
  } else if (i < 1064960 + 294912 + 98304) {
    q = i - (1064960 + 294912); src = wout; dst = woutb;
  } else {
    int qq = i - (1064960 + 294912 + 98304);
    int e = qq * 4;
    int rd = e >> 6;
    int n = 1024 + (e & 63);
    uint2 z; z.x = 0u; z.y = 0u;
    *(uint2*)&vT[(size_t)rd * 1088 + n] = z;
    return;
  }
  float4 v = make_float4(0.f, 0.f, 0.f, 0.f);
  if (!zero) v = *(const float4*)&src[(size_t)q * 4];
  uint2 p;
  p.x = pk2(v.x, v.y);
  p.y = pk2(v.z, v.w);
  *(uint2*)&dst[(size_t)q * 4] = p;
}

// Tiled bf16 GEMM: C[M][Ncols] = A[M][K] * Bt[Ncols][K]^T, 128xBN tile, BK=64.
// EPI=0 (BN=128): scatter into q/k (B,H,1088,64) (q pre-scaled) and V transposed into vT.
// EPI=1 (BN=64): +bias, fp32 out, row<8200.
template <int EPI, int BN>
__global__ __launch_bounds__(256) void k_gemm(const bf16* __restrict__ A,
                                              const bf16* __restrict__ Bt, int K,
                                              bf16* __restrict__ q, bf16* __restrict__ kk,
                                              bf16* __restrict__ vt,
                                              const float* __restrict__ bias,
                                              float* __restrict__ out) {
  __shared__ __attribute__((aligned(16))) bf16 sA[128 * 64];
  __shared__ __attribute__((aligned(16))) bf16 sB[BN * 64];
  constexpr int MF = (BN == 128) ? 4 : 2;          // 16-row frags per wave (M)
  constexpr int WROWS = (BN == 128) ? 64 : 32;     // rows per wave
  const int tid = threadIdx.x;
  const int lane = tid & 63;
  const int w = tid >> 6;
  const int wr = (BN == 128) ? (w >> 1) : w;
  const int wc = (BN == 128) ? (w & 1) : 0;
  const int tn = blockIdx.x, tm = blockIdx.y;
  const int l15 = lane & 15, l4 = lane >> 4;
  const int srow = lane >> 3, sslot = lane & 7;

  f32x4 acc[MF][4] = {};

  const int Ksteps = K >> 6;
  for (int kt = 0; kt < Ksteps; ++kt) {
    __syncthreads();
#pragma unroll
    for (int i = 0; i < 4; ++i) {
      int row = w * 32 + i * 8 + srow;                 // 0..127
      int clog = sslot ^ (row & 7);
      gload_lds16(A + ((size_t)(tm * 128 + row) * K + kt * 64 + clog * 8),
                  &sA[(w * 32 + i * 8) * 64]);
    }
#pragma unroll
    for (int i = 0; i < BN / 32; ++i) {
      int row = w * (BN / 4) + i * 8 + srow;           // 0..BN-1
      int clog = sslot ^ (row & 7);
      gload_lds16(Bt + ((size_t)(tn * BN + row) * K + kt * 64 + clog * 8),
                  &sB[(w * (BN / 4) + i * 8) * 64]);
    }
    __syncthreads();
#pragma unroll
    for (int ks = 0; ks < 2; ++ks) {
      bf16x8 af[MF], bfr[4];
#pragma unroll
      for (int mf = 0; mf < MF; ++mf) {
        int row = wr * WROWS + mf * 16 + l15;
        int phys = (ks * 4 + l4) ^ (row & 7);
        af[mf] = *(const bf16x8*)&sA[row * 64 + phys * 8];
      }
#pragma unroll
      for (int nf = 0; nf < 4; ++nf) {
        int row = wc * 64 + nf * 16 + l15;
        int phys = (ks * 4 + l4) ^ (row & 7);
        bfr[nf] = *(const bf16x8*)&sB[row * 64 + phys * 8];
      }
#pragma unroll
      for (int mf = 0; mf < MF; ++mf)
#pragma unroll
        for (int nf = 0; nf < 4; ++nf)
          acc[mf][nf] =
              __builtin_amdgcn_mfma_f32_16x16x32_bf16(af[mf], bfr[nf], acc[mf][nf], 0, 0, 0);
    }
  }

  const int Rbase = tm * 128 + wr * WROWS + l4 * 4;
  const int Cbase = tn * BN + wc * 64 + l15;
#pragma unroll
  for (int mf = 0; mf < MF; ++mf) {
    int R0 = Rbase + mf * 16;      // 4-aligned; 8200 is 4-aligned -> all-or-none valid
    if (R0 >= 8200) continue;
    if (EPI == 0) {
      int b = R0 / 1025;
      int n0 = R0 - b * 1025;
      bool sb = (n0 + 3 <= 1024);  // all 4 rows in same batch
#pragma unroll
      for (int nf = 0; nf < 4; ++nf) {
        int Cc = Cbase + nf * 16;
        int seg = (Cc >= 1536) ? 2 : (Cc >= 768 ? 1 : 0);
        int inner = Cc - seg * 768;
        int h = inner >> 6, d = inner & 63;
        if (seg == 2) {
          if (sb) {
            uint2 p;
            p.x = pk2(acc[mf][nf][0], acc[mf][nf][1]);
            p.y = pk2(acc[mf][nf][2], acc[mf][nf][3]);
            *(uint2*)&vt[(((size_t)b * 12 + h) * 64 + d) * 1088 + n0] = p;
          } else {
#pragma unroll
            for (int r = 0; r < 4; ++r) {
              int R = R0 + r;
              int b2 = R / 1025;
              int n = R - b2 * 1025;
              vt[(((size_t)b2 * 12 + h) * 64 + d) * 1088 + n] = (bf16)acc[mf][nf][r];
            }
          }
        } else {
          bf16* dst = seg ? kk : q;
          float scl = seg ? 1.f : QSCALE;
#pragma unroll
          for (int r = 0; r < 4; ++r) {
            int b2, n;
            if (sb) { b2 = b; n = n0 + r; }
            else { int R = R0 + r; b2 = R / 1025; n = R - b2 * 1025; }
            dst[(((size_t)b2 * 12 + h) * 1088 + n) * 64 + d] = (bf16)(acc[mf][nf][r] * scl);
          }
        }
      }
    } else {
#pragma unroll
      for (int r = 0; r < 4; ++r) {
        int R = R0 + r;
#pragma unroll
        for (int nf = 0; nf < 4; ++nf) {
          int Cc = Cbase + nf * 16;
          out[(size_t)R * 512 + Cc] = acc[mf][nf][r] + bias[Cc];
        }
      }
    }
  }
}

// Flash attention, swapped-QK^T, double-buffered K/V, defer-max, setprio.
// LDS = 40960 B exactly -> 4 blocks/CU. 1D grid 864 with XCD-contiguous heads.
__global__ __launch_bounds__(256, 4) void k_flash(const bf16* __restrict__ qg,
                                                  const bf16* __restrict__ kg,
                                                  const bf16* __restrict__ vtg,
                                                  bf16* __restrict__ outb) {
  __shared__ __attribute__((aligned(16))) bf16 sK[2][64 * 64];
  __shared__ __attribute__((aligned(16))) bf16 sV[2][64 * 64];
  __shared__ __attribute__((aligned(16))) bf16 sP[4][16 * 64];  // XOR-swizzled, stride 64
  const int tid = threadIdx.x, lane = tid & 63, w = tid >> 6;
  const int l15 = lane & 15, l4 = lane >> 4;
  // XCD-contiguous mapping: all 9 q-blocks of a head on one XCD (864 = 8 * 108)
  const int wg = blockIdx.x;
  const int logical = (wg & 7) * 108 + (wg >> 3);
  const int bh = logical / 9, qgp = logical - bh * 9;
  const int b = bh / 12, h = bh - b * 12;
  const int srow = lane >> 3, sslot = lane & 7;
  const int nsub = (qgp == 8) ? 1 : 2;
  const int swz = (l15 & 7) << 3;  // sP row-XOR (bf16 units)

  // Q fragments (pre-scaled by QSCALE in the QKV GEMM epilogue)
  bf16x8 qf[2][2];
#pragma unroll
  for (int s = 0; s < 2; ++s) {
    if (s < nsub) {
      size_t qoff = ((size_t)bh * 1088 + (qgp * 2 + s) * 64 + w * 16 + l15) * 64 + l4 * 8;
      qf[s][0] = *(const bf16x8*)&qg[qoff];
      qf[s][1] = *(const bf16x8*)&qg[qoff + 32];
    }
  }

  float mreg[2] = {-INFINITY, -INFINITY};
  float lreg[2] = {0.f, 0.f};
  f32x4 oa[2][4] = {};

  const int px0 = (l4 ^ (l15 & 7)) * 8;        // K/V LDS swizzled chunk, ks=0
  const int px1 = ((4 + l4) ^ (l15 & 7)) * 8;  // ks=1
  const int stRow = (w * 16 + srow) * 64;
  const int stRow2 = (w * 16 + 8 + srow) * 64;

  auto STAGE = [&](int bi, int t) {
    int row = w * 16 + srow;
    int clog = sslot ^ (row & 7);
    gload_lds16(kg + ((size_t)bh * 1088 + t * 64 + row) * 64 + clog * 8, &sK[bi][stRow]);
    gload_lds16(vtg + ((size_t)bh * 64 + row) * 1088 + t * 64 + clog * 8, &sV[bi][stRow]);
    int row2 = row + 8;
    int clog2 = sslot ^ (row2 & 7);
    gload_lds16(kg + ((size_t)bh * 1088 + t * 64 + row2) * 64 + clog2 * 8, &sK[bi][stRow2]);
    gload_lds16(vtg + ((size_t)bh * 64 + row2) * 1088 + t * 64 + clog2 * 8, &sV[bi][stRow2]);
  };

  STAGE(0, 0);
  __syncthreads();
  int cur = 0;

  for (int t = 0; t < 17; ++t) {
    if (t < 16) STAGE(cur ^ 1, t + 1);
    const bf16* kb_ = sK[cur];
    const bf16* vb_ = sV[cur];

    bf16x8 af[2][4], vf[2][4];
#pragma unroll
    for (int jt = 0; jt < 4; ++jt) {
      af[0][jt] = *(const bf16x8*)&kb_[(jt * 16 + l15) * 64 + px0];
      af[1][jt] = *(const bf16x8*)&kb_[(jt * 16 + l15) * 64 + px1];
      vf[0][jt] = *(const bf16x8*)&vb_[(jt * 16 + l15) * 64 + px0];
      vf[1][jt] = *(const bf16x8*)&vb_[(jt * 16 + l15) * 64 + px1];
    }

#pragma unroll
    for (int s = 0; s < 2; ++s) {
      if (s >= nsub) continue;
      // S^T = K · Q^T : lane holds S[q=l15][kv = jt*16 + l4*4 + r]
      f32x4 sc[4] = {};
      __builtin_amdgcn_s_setprio(1);
#pragma unroll
      for (int ks = 0; ks < 2; ++ks)
#pragma unroll
        for (int jt = 0; jt < 4; ++jt)
          sc[jt] = __builtin_amdgcn_mfma_f32_16x16x32_bf16(af[ks][jt], qf[s][ks], sc[jt], 0, 0, 0);
      __builtin_amdgcn_s_setprio(0);

      if (t == 16) {  // only kv=1024 is valid in the tail tile
#pragma unroll
        for (int jt = 0; jt < 4; ++jt)
#pragma unroll
          for (int r = 0; r < 4; ++r) {
            if (jt == 0 && r == 0)
              sc[jt][r] = (l4 == 0) ? sc[jt][r] : -INFINITY;
            else
              sc[jt][r] = -INFINITY;
          }
      }

      float pm = fmaxf(fmaxf(fmaxf(sc[0][0], sc[0][1]), fmaxf(sc[0][2], sc[0][3])),
                       fmaxf(fmaxf(sc[1][0], sc[1][1]), fmaxf(sc[1][2], sc[1][3])));
      float pm2 = fmaxf(fmaxf(fmaxf(sc[2][0], sc[2][1]), fmaxf(sc[2][2], sc[2][3])),
                        fmaxf(fmaxf(sc[3][0], sc[3][1]), fmaxf(sc[3][2], sc[3][3])));
      pm = fmaxf(pm, pm2);
      pm = fmaxf(pm, __shfl_xor(pm, 16));
      pm = fmaxf(pm, __shfl_xor(pm, 32));

      if (__any(pm > mreg[s] + 8.0f)) {
        float mn = fmaxf(mreg[s], pm);
        float alpha = fexp2(mreg[s] - mn);
        mreg[s] = mn;
        lreg[s] *= alpha;
        float ar[4];
#pragma unroll
        for (int r = 0; r < 4; ++r) ar[r] = __shfl(alpha, l4 * 4 + r);
#pragma unroll
        for (int db = 0; db < 4; ++db)
#pragma unroll
          for (int r = 0; r < 4; ++r) oa[s][db][r] *= ar[r];
      }
      float mn = mreg[s];

      float rs = 0.f;
#pragma unroll
      for (int jt = 0; jt < 4; ++jt) {
        float p0 = fexp2(sc[jt][0] - mn);
        float p1 = fexp2(sc[jt][1] - mn);
        float p2 = fexp2(sc[jt][2] - mn);
        float p3 = fexp2(sc[jt][3] - mn);
        rs += (p0 + p1) + (p2 + p3);
        uint2 pkd;
        pkd.x = pk2(p0, p1);
        pkd.y = pk2(p2, p3);
        *(uint2*)&sP[w][l15 * 64 + ((jt * 16 + l4 * 4) ^ swz)] = pkd;
      }
      rs += __shfl_xor(rs, 16);
      rs += __shfl_xor(rs, 32);
      lreg[s] += rs;

      __builtin_amdgcn_s_setprio(1);
#pragma unroll
      for (int ks = 0; ks < 2; ++ks) {
        bf16x8 pf = *(const bf16x8*)&sP[w][l15 * 64 + ((ks * 32 + l4 * 8) ^ swz)];
#pragma unroll
        for (int db = 0; db < 4; ++db)
          oa[s][db] = __builtin_amdgcn_mfma_f32_16x16x32_bf16(pf, vf[ks][db], oa[s][db], 0, 0, 0);
      }
      __builtin_amdgcn_s_setprio(0);
    }
    __syncthreads();
    cur ^= 1;
  }

#pragma unroll
  for (int s = 0; s < 2; ++s) {
    if (s >= nsub) continue;
    float linv = frcp(lreg[s]);
#pragma unroll
    for (int r = 0; r < 4; ++r) {
      float ir = __shfl(linv, l4 * 4 + r);
      int n = (qgp * 2 + s) * 64 + w * 16 + l4 * 4 + r;
      if (n >= 1025) continue;
#pragma unroll
      for (int db = 0; db < 4; ++db)
        outb[((size_t)b * 1025 + n) * 768 + h * 64 + db * 16 + l15] = (bf16)(oa[s][db][r] * ir);
    }
  }
}

// Depthwise 3x3 conv (SAME), rolling-column, 8 output columns per block.
// RMW-add into outb[:, :, 0:512]. Grid (8, 32, 4).
__global__ __launch_bounds__(256) void k_local(const float* __restrict__ x,
                                               const float* __restrict__ wdw,
                                               bf16* __restrict__ outb) {
  const int b = blockIdx.x, y = blockIdx.y, xseg = blockIdx.z, c0 = threadIdx.x;
  const int x0 = xseg * 8;
  const bool hm = (y > 0), hp = (y < 31);
#pragma unroll
  for (int hf = 0; hf < 2; ++hf) {
    const int c = hf * 256 + c0;
    float w9[9];
#pragma unroll
    for (int k = 0; k < 9; ++k) w9[k] = wdw[(size_t)c * 9 + k];
    const float* xb = x + ((size_t)b * 1025 + 1) * 512 + c;
    float A = 0.f, Bp = 0.f;
    for (int cc = x0 - 1; cc <= x0 + 8; ++cc) {
      float v0 = 0.f, v1 = 0.f, v2 = 0.f;
      if (cc >= 0 && cc < 32) {
        v1 = xb[((size_t)y * 32 + cc) * 512];
        if (hm) v0 = xb[((size_t)(y - 1) * 32 + cc) * 512];
        if (hp) v2 = xb[((size_t)(y + 1) * 32 + cc) * 512];
      }
      float t0 = v0 * w9[0] + v1 * w9[3] + v2 * w9[6];
      float t1 = v0 * w9[1] + v1 * w9[4] + v2 * w9[7];
      float t2 = v0 * w9[2] + v1 * w9[5] + v2 * w9[8];
      int oc = cc - 1;
      if (oc >= x0 && oc <= x0 + 7) {
        float acc = A + t2;
        size_t o = ((size_t)b * 1025 + 1 + y * 32 + oc) * 768 + c;
        outb[o] = (bf16)((float)outb[o] + acc);
      }
      A = Bp + t1;
      Bp = t0;
    }
  }
  if (y == 0 && xseg == 0) {
#pragma unroll
    for (int hf = 0; hf < 2; ++hf) {
      int c = hf * 256 + c0;
      size_t o = ((size_t)b * 1025) * 768 + c;
      outb[o] = (bf16)((float)outb[o] + x[((size_t)b * 1025) * 512 + c]);
    }
  }
}

extern "C" void kernel_launch(void* const* d_in, const int* in_sizes, int n_in,
                              void* d_out, int out_size, void* d_ws, size_t ws_size,
                              hipStream_t stream) {
  const float* x = (const float*)d_in[0];
  const float* w_qkv = (const float*)d_in[1];
  const float* w_dw = (const float*)d_in[2];
  const float* w_out = (const float*)d_in[3];
  const float* b_out = (const float*)d_in[4];
  float* out = (float*)d_out;

  char* ws = (char*)d_ws;
  size_t off = 0;
  auto alloc = [&](size_t bytes) {
    char* p = ws + off;
    off = (off + bytes + 255) & ~(size_t)255;
    return p;
  };
  bf16* xb    = (bf16*)alloc((size_t)8320 * 512 * 2);
  bf16* wqkvb = (bf16*)alloc((size_t)2304 * 512 * 2);
  bf16* woutb = (bf16*)alloc((size_t)512 * 768 * 2);
  bf16* qb    = (bf16*)alloc((size_t)96 * 1088 * 64 * 2);
  bf16* kb    = (bf16*)alloc((size_t)96 * 1088 * 64 * 2);
  bf16* vT    = (bf16*)alloc((size_t)96 * 64 * 1088 * 2);
  bf16* outb  = (bf16*)alloc((size_t)8320 * 768 * 2);

  k_prep<<<6080, 256, 0, stream>>>(x, w_qkv, w_out, xb, wqkvb, woutb, vT);
  k_gemm<0, 128><<<dim3(18, 65), 256, 0, stream>>>(xb, wqkvb, 512, qb, kb, vT, nullptr, nullptr);
  k_flash<<<864, 256, 0, stream>>>(qb, kb, vT, outb);
  k_local<<<dim3(8, 32, 4), 256, 0, stream>>>(x, w_dw, outb);
  k_gemm<1, 64><<<dim3(8, 65), 256, 0, stream>>>(outb, woutb, 768, nullptr, nullptr, nullptr,
                                                 b_out, out);
}

// Round 5
// 158.888 us; speedup vs baseline: 1.4317x; 1.4317x over previous
//
#include <hip/hip_runtime.h>
#include <hip/hip_bf16.h>
#include <stdint.h>
#include <math.h>

typedef __bf16 bf16;
typedef __bf16 bf16x8 __attribute__((ext_vector_type(8)));
typedef float f32x4 __attribute__((ext_vector_type(4)));

#define QSCALE 0.1803368801111f  /* 0.125 * log2(e) */

// B=8, N=1025 (32*32+1), DIM=512, HEADS=12, DH=64, INNER=768
// M = 8*1025 = 8200, padded to 8320 (65*128). N per (b,h) padded to 1088 (17*64).

__device__ __forceinline__ void gload_lds16(const void* g, void* l) {
  typedef const __attribute__((address_space(1))) char g_char;
  typedef __attribute__((address_space(3))) char l_char;
  g_char* gp = (g_char*)(uintptr_t)g;
  l_char* lp = (l_char*)(uint32_t)(uintptr_t)l;
  __builtin_amdgcn_global_load_lds(gp, lp, 16, 0, 0);
}

__device__ __forceinline__ float fexp2(float x) {
#if __has_builtin(__builtin_amdgcn_exp2f)
  return __builtin_amdgcn_exp2f(x);
#else
  return exp2f(x);
#endif
}

__device__ __forceinline__ float frcp(float x) {
#if __has_builtin(__builtin_amdgcn_rcpf)
  return __builtin_amdgcn_rcpf(x);
#else
  return 1.f / x;
#endif
}

__device__ __forceinline__ uint32_t pk2(float a, float b) {
  union { bf16 h; unsigned short u; } ua, ub;
  ua.h = (bf16)a; ub.h = (bf16)b;
  return (uint32_t)ua.u | ((uint32_t)ub.u << 16);
}

// Fused prep: x->xb (pad to 8320 rows), w_qkv->bf16, w_out->bf16, zero vT tail cols [1024,1088).
__global__ __launch_bounds__(256) void k_prep(const float* __restrict__ x,
                                              const float* __restrict__ wqkv,
                                              const float* __restrict__ wout,
                                              bf16* __restrict__ xb, bf16* __restrict__ wqkvb,
                                              bf16* __restrict__ woutb, bf16* __restrict__ vT) {
  int i = blockIdx.x * 256 + threadIdx.x;
  const float* src = nullptr;
  bf16* dst = nullptr;
  int q = i;
  bool zero = false;
  if (i < 1064960) {
    if (i < 1049600) src = x; else zero = true;
    dst = xb;
  } else if (i < 1064960 + 294912) {
    q = i - 1064960; src = wqkv; dst = wqkvb;
  } else if (i < 1064960 + 294912 + 98304) {
    q = i - (1064960 + 294912); src = wout; dst = woutb;
  } else {
    int qq = i - (1064960 + 294912 + 98304);
    int e = qq * 4;
    int rd = e >> 6;
    int n = 1024 + (e & 63);
    uint2 z; z.x = 0u; z.y = 0u;
    *(uint2*)&vT[(size_t)rd * 1088 + n] = z;
    return;
  }
  float4 v = make_float4(0.f, 0.f, 0.f, 0.f);
  if (!zero) v = *(const float4*)&src[(size_t)q * 4];
  uint2 p;
  p.x = pk2(v.x, v.y);
  p.y = pk2(v.z, v.w);
  *(uint2*)&dst[(size_t)q * 4] = p;
}

// Tiled bf16 GEMM: C[M][Ncols] = A[M][K] * Bt[Ncols][K]^T, 128xBN tile, BK=64.
// EPI=0 (BN=128): scatter into q/k (B,H,1088,64) (q pre-scaled) and V transposed into vT.
// EPI=1 (BN=64): +bias, fp32 out, row<8200.
template <int EPI, int BN>
__global__ __launch_bounds__(256) void k_gemm(const bf16* __restrict__ A,
                                              const bf16* __restrict__ Bt, int K,
                                              bf16* __restrict__ q, bf16* __restrict__ kk,
                                              bf16* __restrict__ vt,
                                              const float* __restrict__ bias,
                                              float* __restrict__ out) {
  __shared__ __attribute__((aligned(16))) bf16 sA[128 * 64];
  __shared__ __attribute__((aligned(16))) bf16 sB[BN * 64];
  constexpr int MF = (BN == 128) ? 4 : 2;          // 16-row frags per wave (M)
  constexpr int WROWS = (BN == 128) ? 64 : 32;     // rows per wave
  const int tid = threadIdx.x;
  const int lane = tid & 63;
  const int w = tid >> 6;
  const int wr = (BN == 128) ? (w >> 1) : w;
  const int wc = (BN == 128) ? (w & 1) : 0;
  const int tn = blockIdx.x, tm = blockIdx.y;
  const int l15 = lane & 15, l4 = lane >> 4;
  const int srow = lane >> 3, sslot = lane & 7;

  f32x4 acc[MF][4] = {};

  const int Ksteps = K >> 6;
  for (int kt = 0; kt < Ksteps; ++kt) {
    __syncthreads();
#pragma unroll
    for (int i = 0; i < 4; ++i) {
      int row = w * 32 + i * 8 + srow;                 // 0..127
      int clog = sslot ^ (row & 7);
      gload_lds16(A + ((size_t)(tm * 128 + row) * K + kt * 64 + clog * 8),
                  &sA[(w * 32 + i * 8) * 64]);
    }
#pragma unroll
    for (int i = 0; i < BN / 32; ++i) {
      int row = w * (BN / 4) + i * 8 + srow;           // 0..BN-1
      int clog = sslot ^ (row & 7);
      gload_lds16(Bt + ((size_t)(tn * BN + row) * K + kt * 64 + clog * 8),
                  &sB[(w * (BN / 4) + i * 8) * 64]);
    }
    __syncthreads();
#pragma unroll
    for (int ks = 0; ks < 2; ++ks) {
      bf16x8 af[MF], bfr[4];
#pragma unroll
      for (int mf = 0; mf < MF; ++mf) {
        int row = wr * WROWS + mf * 16 + l15;
        int phys = (ks * 4 + l4) ^ (row & 7);
        af[mf] = *(const bf16x8*)&sA[row * 64 + phys * 8];
      }
#pragma unroll
      for (int nf = 0; nf < 4; ++nf) {
        int row = wc * 64 + nf * 16 + l15;
        int phys = (ks * 4 + l4) ^ (row & 7);
        bfr[nf] = *(const bf16x8*)&sB[row * 64 + phys * 8];
      }
#pragma unroll
      for (int mf = 0; mf < MF; ++mf)
#pragma unroll
        for (int nf = 0; nf < 4; ++nf)
          acc[mf][nf] =
              __builtin_amdgcn_mfma_f32_16x16x32_bf16(af[mf], bfr[nf], acc[mf][nf], 0, 0, 0);
    }
  }

  const int Rbase = tm * 128 + wr * WROWS + l4 * 4;
  const int Cbase = tn * BN + wc * 64 + l15;
#pragma unroll
  for (int mf = 0; mf < MF; ++mf) {
    int R0 = Rbase + mf * 16;      // 4-aligned; 8200 is 4-aligned -> all-or-none valid
    if (R0 >= 8200) continue;
    if (EPI == 0) {
      int b = R0 / 1025;
      int n0 = R0 - b * 1025;
      bool sb = (n0 + 3 <= 1024);  // all 4 rows in same batch
#pragma unroll
      for (int nf = 0; nf < 4; ++nf) {
        int Cc = Cbase + nf * 16;
        int seg = (Cc >= 1536) ? 2 : (Cc >= 768 ? 1 : 0);
        int inner = Cc - seg * 768;
        int h = inner >> 6, d = inner & 63;
        if (seg == 2) {
          if (sb) {
            uint2 p;
            p.x = pk2(acc[mf][nf][0], acc[mf][nf][1]);
            p.y = pk2(acc[mf][nf][2], acc[mf][nf][3]);
            *(uint2*)&vt[(((size_t)b * 12 + h) * 64 + d) * 1088 + n0] = p;
          } else {
#pragma unroll
            for (int r = 0; r < 4; ++r) {
              int R = R0 + r;
              int b2 = R / 1025;
              int n = R - b2 * 1025;
              vt[(((size_t)b2 * 12 + h) * 64 + d) * 1088 + n] = (bf16)acc[mf][nf][r];
            }
          }
        } else {
          bf16* dst = seg ? kk : q;
          float scl = seg ? 1.f : QSCALE;
#pragma unroll
          for (int r = 0; r < 4; ++r) {
            int b2, n;
            if (sb) { b2 = b; n = n0 + r; }
            else { int R = R0 + r; b2 = R / 1025; n = R - b2 * 1025; }
            dst[(((size_t)b2 * 12 + h) * 1088 + n) * 64 + d] = (bf16)(acc[mf][nf][r] * scl);
          }
        }
      }
    } else {
#pragma unroll
      for (int r = 0; r < 4; ++r) {
        int R = R0 + r;
#pragma unroll
        for (int nf = 0; nf < 4; ++nf) {
          int Cc = Cbase + nf * 16;
          out[(size_t)R * 512 + Cc] = acc[mf][nf][r] + bias[Cc];
        }
      }
    }
  }
}

// Flash attention, swapped-QK^T, double-buffered K/V, defer-max, setprio.
// LDS = 40960 B exactly; ~108 VGPR -> 4 waves/SIMD -> 4 blocks/CU naturally.
// NOTE: do NOT add a min-waves launch_bounds here — (256,4) capped VGPRs and
// caused 250 MB of scratch spill (round 4: 77us -> 151us).
__global__ __launch_bounds__(256) void k_flash(const bf16* __restrict__ qg,
                                               const bf16* __restrict__ kg,
                                               const bf16* __restrict__ vtg,
                                               bf16* __restrict__ outb) {
  __shared__ __attribute__((aligned(16))) bf16 sK[2][64 * 64];
  __shared__ __attribute__((aligned(16))) bf16 sV[2][64 * 64];
  __shared__ __attribute__((aligned(16))) bf16 sP[4][16 * 64];  // XOR-swizzled, stride 64
  const int tid = threadIdx.x, lane = tid & 63, w = tid >> 6;
  const int l15 = lane & 15, l4 = lane >> 4;
  // XCD-contiguous mapping: all 9 q-blocks of a head on one XCD (864 = 8 * 108)
  const int wg = blockIdx.x;
  const int logical = (wg & 7) * 108 + (wg >> 3);
  const int bh = logical / 9, qgp = logical - bh * 9;
  const int b = bh / 12, h = bh - b * 12;
  const int srow = lane >> 3, sslot = lane & 7;
  const int nsub = (qgp == 8) ? 1 : 2;
  const int swz = (l15 & 7) << 3;  // sP row-XOR (bf16 units)

  // Q fragments (pre-scaled by QSCALE in the QKV GEMM epilogue)
  bf16x8 qf[2][2];
#pragma unroll
  for (int s = 0; s < 2; ++s) {
    if (s < nsub) {
      size_t qoff = ((size_t)bh * 1088 + (qgp * 2 + s) * 64 + w * 16 + l15) * 64 + l4 * 8;
      qf[s][0] = *(const bf16x8*)&qg[qoff];
      qf[s][1] = *(const bf16x8*)&qg[qoff + 32];
    }
  }

  float mreg[2] = {-INFINITY, -INFINITY};
  float lreg[2] = {0.f, 0.f};
  f32x4 oa[2][4] = {};

  const int px0 = (l4 ^ (l15 & 7)) * 8;        // K/V LDS swizzled chunk, ks=0
  const int px1 = ((4 + l4) ^ (l15 & 7)) * 8;  // ks=1
  const int stRow = (w * 16 + srow) * 64;
  const int stRow2 = (w * 16 + 8 + srow) * 64;

  auto STAGE = [&](int bi, int t) {
    int row = w * 16 + srow;
    int clog = sslot ^ (row & 7);
    gload_lds16(kg + ((size_t)bh * 1088 + t * 64 + row) * 64 + clog * 8, &sK[bi][stRow]);
    gload_lds16(vtg + ((size_t)bh * 64 + row) * 1088 + t * 64 + clog * 8, &sV[bi][stRow]);
    int row2 = row + 8;
    int clog2 = sslot ^ (row2 & 7);
    gload_lds16(kg + ((size_t)bh * 1088 + t * 64 + row2) * 64 + clog2 * 8, &sK[bi][stRow2]);
    gload_lds16(vtg + ((size_t)bh * 64 + row2) * 1088 + t * 64 + clog2 * 8, &sV[bi][stRow2]);
  };

  STAGE(0, 0);
  __syncthreads();
  int cur = 0;

  for (int t = 0; t < 17; ++t) {
    if (t < 16) STAGE(cur ^ 1, t + 1);
    const bf16* kb_ = sK[cur];
    const bf16* vb_ = sV[cur];

    bf16x8 af[2][4], vf[2][4];
#pragma unroll
    for (int jt = 0; jt < 4; ++jt) {
      af[0][jt] = *(const bf16x8*)&kb_[(jt * 16 + l15) * 64 + px0];
      af[1][jt] = *(const bf16x8*)&kb_[(jt * 16 + l15) * 64 + px1];
      vf[0][jt] = *(const bf16x8*)&vb_[(jt * 16 + l15) * 64 + px0];
      vf[1][jt] = *(const bf16x8*)&vb_[(jt * 16 + l15) * 64 + px1];
    }

#pragma unroll
    for (int s = 0; s < 2; ++s) {
      if (s >= nsub) continue;
      // S^T = K · Q^T : lane holds S[q=l15][kv = jt*16 + l4*4 + r]
      f32x4 sc[4] = {};
      __builtin_amdgcn_s_setprio(1);
#pragma unroll
      for (int ks = 0; ks < 2; ++ks)
#pragma unroll
        for (int jt = 0; jt < 4; ++jt)
          sc[jt] = __builtin_amdgcn_mfma_f32_16x16x32_bf16(af[ks][jt], qf[s][ks], sc[jt], 0, 0, 0);
      __builtin_amdgcn_s_setprio(0);

      if (t == 16) {  // only kv=1024 is valid in the tail tile
#pragma unroll
        for (int jt = 0; jt < 4; ++jt)
#pragma unroll
          for (int r = 0; r < 4; ++r) {
            if (jt == 0 && r == 0)
              sc[jt][r] = (l4 == 0) ? sc[jt][r] : -INFINITY;
            else
              sc[jt][r] = -INFINITY;
          }
      }

      float pm = fmaxf(fmaxf(fmaxf(sc[0][0], sc[0][1]), fmaxf(sc[0][2], sc[0][3])),
                       fmaxf(fmaxf(sc[1][0], sc[1][1]), fmaxf(sc[1][2], sc[1][3])));
      float pm2 = fmaxf(fmaxf(fmaxf(sc[2][0], sc[2][1]), fmaxf(sc[2][2], sc[2][3])),
                        fmaxf(fmaxf(sc[3][0], sc[3][1]), fmaxf(sc[3][2], sc[3][3])));
      pm = fmaxf(pm, pm2);
      pm = fmaxf(pm, __shfl_xor(pm, 16));
      pm = fmaxf(pm, __shfl_xor(pm, 32));

      if (__any(pm > mreg[s] + 8.0f)) {
        float mn = fmaxf(mreg[s], pm);
        float alpha = fexp2(mreg[s] - mn);
        mreg[s] = mn;
        lreg[s] *= alpha;
        float ar[4];
#pragma unroll
        for (int r = 0; r < 4; ++r) ar[r] = __shfl(alpha, l4 * 4 + r);
#pragma unroll
        for (int db = 0; db < 4; ++db)
#pragma unroll
          for (int r = 0; r < 4; ++r) oa[s][db][r] *= ar[r];
      }
      float mn = mreg[s];

      float rs = 0.f;
#pragma unroll
      for (int jt = 0; jt < 4; ++jt) {
        float p0 = fexp2(sc[jt][0] - mn);
        float p1 = fexp2(sc[jt][1] - mn);
        float p2 = fexp2(sc[jt][2] - mn);
        float p3 = fexp2(sc[jt][3] - mn);
        rs += (p0 + p1) + (p2 + p3);
        uint2 pkd;
        pkd.x = pk2(p0, p1);
        pkd.y = pk2(p2, p3);
        *(uint2*)&sP[w][l15 * 64 + ((jt * 16 + l4 * 4) ^ swz)] = pkd;
      }
      rs += __shfl_xor(rs, 16);
      rs += __shfl_xor(rs, 32);
      lreg[s] += rs;

      __builtin_amdgcn_s_setprio(1);
#pragma unroll
      for (int ks = 0; ks < 2; ++ks) {
        bf16x8 pf = *(const bf16x8*)&sP[w][l15 * 64 + ((ks * 32 + l4 * 8) ^ swz)];
#pragma unroll
        for (int db = 0; db < 4; ++db)
          oa[s][db] = __builtin_amdgcn_mfma_f32_16x16x32_bf16(pf, vf[ks][db], oa[s][db], 0, 0, 0);
      }
      __builtin_amdgcn_s_setprio(0);
    }
    __syncthreads();
    cur ^= 1;
  }

#pragma unroll
  for (int s = 0; s < 2; ++s) {
    if (s >= nsub) continue;
    float linv = frcp(lreg[s]);
#pragma unroll
    for (int r = 0; r < 4; ++r) {
      float ir = __shfl(linv, l4 * 4 + r);
      int n = (qgp * 2 + s) * 64 + w * 16 + l4 * 4 + r;
      if (n >= 1025) continue;
#pragma unroll
      for (int db = 0; db < 4; ++db)
        outb[((size_t)b * 1025 + n) * 768 + h * 64 + db * 16 + l15] = (bf16)(oa[s][db][r] * ir);
    }
  }
}

// Depthwise 3x3 conv (SAME), rolling-column, 8 output columns per block.
// RMW-add into outb[:, :, 0:512]. Grid (8, 32, 4).
__global__ __launch_bounds__(256) void k_local(const float* __restrict__ x,
                                               const float* __restrict__ wdw,
                                               bf16* __restrict__ outb) {
  const int b = blockIdx.x, y = blockIdx.y, xseg = blockIdx.z, c0 = threadIdx.x;
  const int x0 = xseg * 8;
  const bool hm = (y > 0), hp = (y < 31);
#pragma unroll
  for (int hf = 0; hf < 2; ++hf) {
    const int c = hf * 256 + c0;
    float w9[9];
#pragma unroll
    for (int k = 0; k < 9; ++k) w9[k] = wdw[(size_t)c * 9 + k];
    const float* xb = x + ((size_t)b * 1025 + 1) * 512 + c;
    float A = 0.f, Bp = 0.f;
    for (int cc = x0 - 1; cc <= x0 + 8; ++cc) {
      float v0 = 0.f, v1 = 0.f, v2 = 0.f;
      if (cc >= 0 && cc < 32) {
        v1 = xb[((size_t)y * 32 + cc) * 512];
        if (hm) v0 = xb[((size_t)(y - 1) * 32 + cc) * 512];
        if (hp) v2 = xb[((size_t)(y + 1) * 32 + cc) * 512];
      }
      float t0 = v0 * w9[0] + v1 * w9[3] + v2 * w9[6];
      float t1 = v0 * w9[1] + v1 * w9[4] + v2 * w9[7];
      float t2 = v0 * w9[2] + v1 * w9[5] + v2 * w9[8];
      int oc = cc - 1;
      if (oc >= x0 && oc <= x0 + 7) {
        float acc = A + t2;
        size_t o = ((size_t)b * 1025 + 1 + y * 32 + oc) * 768 + c;
        outb[o] = (bf16)((float)outb[o] + acc);
      }
      A = Bp + t1;
      Bp = t0;
    }
  }
  if (y == 0 && xseg == 0) {
#pragma unroll
    for (int hf = 0; hf < 2; ++hf) {
      int c = hf * 256 + c0;
      size_t o = ((size_t)b * 1025) * 768 + c;
      outb[o] = (bf16)((float)outb[o] + x[((size_t)b * 1025) * 512 + c]);
    }
  }
}

extern "C" void kernel_launch(void* const* d_in, const int* in_sizes, int n_in,
                              void* d_out, int out_size, void* d_ws, size_t ws_size,
                              hipStream_t stream) {
  const float* x = (const float*)d_in[0];
  const float* w_qkv = (const float*)d_in[1];
  const float* w_dw = (const float*)d_in[2];
  const float* w_out = (const float*)d_in[3];
  const float* b_out = (const float*)d_in[4];
  float* out = (float*)d_out;

  char* ws = (char*)d_ws;
  size_t off = 0;
  auto alloc = [&](size_t bytes) {
    char* p = ws + off;
    off = (off + bytes + 255) & ~(size_t)255;
    return p;
  };
  bf16* xb    = (bf16*)alloc((size_t)8320 * 512 * 2);
  bf16* wqkvb = (bf16*)alloc((size_t)2304 * 512 * 2);
  bf16* woutb = (bf16*)alloc((size_t)512 * 768 * 2);
  bf16* qb    = (bf16*)alloc((size_t)96 * 1088 * 64 * 2);
  bf16* kb    = (bf16*)alloc((size_t)96 * 1088 * 64 * 2);
  bf16* vT    = (bf16*)alloc((size_t)96 * 64 * 1088 * 2);
  bf16* outb  = (bf16*)alloc((size_t)8320 * 768 * 2);

  k_prep<<<6080, 256, 0, stream>>>(x, w_qkv, w_out, xb, wqkvb, woutb, vT);
  k_gemm<0, 128><<<dim3(18, 65), 256, 0, stream>>>(xb, wqkvb, 512, qb, kb, vT, nullptr, nullptr);
  k_flash<<<864, 256, 0, stream>>>(qb, kb, vT, outb);
  k_local<<<dim3(8, 32, 4), 256, 0, stream>>>(x, w_dw, outb);
  k_gemm<1, 64><<<dim3(8, 65), 256, 0, stream>>>(outb, woutb, 768, nullptr, nullptr, nullptr,
                                                 b_out, out);
}